// Round 1
// baseline (313.566 us; speedup 1.0000x reference)
//
#include <hip/hip_runtime.h>
#include <hip/hip_bf16.h>

#define N_NODES 50000
#define N_EDGES 800000
#define NUM_GRAPHS 512
#define DIM 128
#define MAXDEG 64

typedef short short8 __attribute__((ext_vector_type(8)));
typedef float f32x4 __attribute__((ext_vector_type(4)));

__device__ __forceinline__ unsigned short f2bu(float f) {
    __hip_bfloat16 h = __float2bfloat16(f);
    return *reinterpret_cast<unsigned short*>(&h);
}

// ---- adjacency build: count edges per dst, bucket src indices ----
__global__ __launch_bounds__(256) void build_adj_k(const int* __restrict__ ei,
                                                   int* __restrict__ cnt,
                                                   int* __restrict__ adj) {
    int e = blockIdx.x * 256 + threadIdx.x;
    if (e >= N_EDGES) return;
    int s = ei[e];            // row 0: src
    int d = ei[N_EDGES + e];  // row 1: dst
    int slot = atomicAdd(&cnt[d], 1);
    if (slot < MAXDEG) adj[d * MAXDEG + slot] = s;
}

__global__ __launch_bounds__(256) void dinv_k(const int* __restrict__ cnt,
                                              float* __restrict__ dinv) {
    int i = blockIdx.x * 256 + threadIdx.x;
    if (i < N_NODES) dinv[i] = rsqrtf((float)cnt[i] + 1.0f);
}

// ---- f32 -> bf16 convert (x features) ----
__global__ __launch_bounds__(256) void cvt_k(const float* __restrict__ x,
                                             unsigned short* __restrict__ xb) {
    int i = blockIdx.x * 256 + threadIdx.x;  // one float4 per thread, exact grid
    const float4 v = ((const float4*)x)[i];
    ushort4 o;
    o.x = f2bu(v.x); o.y = f2bu(v.y); o.z = f2bu(v.z); o.w = f2bu(v.w);
    ((ushort4*)xb)[i] = o;
}

// ---- GEMM: hs[r][c] = dinv[r] * sum_k A[r][k] * W[k][c]  (bf16 MFMA 16x16x32) ----
// One block = 4 waves = 64 rows; W (bf16, transposed, padded stride 136) in LDS.
__global__ __launch_bounds__(256) void gemm_k(const unsigned short* __restrict__ Ab,
                                              const float* __restrict__ W,
                                              const float* __restrict__ dinv,
                                              float* __restrict__ C, int M) {
    __shared__ unsigned short Wt[128 * 136];  // Wt[n][k], 34.8 KB
    int t = threadIdx.x;
    for (int idx = t; idx < 16384; idx += 256) {
        int k = idx >> 7, n = idx & 127;
        Wt[n * 136 + k] = f2bu(W[idx]);  // coalesced read of W[k][n]
    }
    __syncthreads();

    int wave = t >> 6, lane = t & 63;
    int quad = lane >> 4, ln = lane & 15;
    int rb = blockIdx.x * 64 + wave * 16;
    if (rb + 16 > M) return;

    // A fragments: A[m=ln][k=quad*8+j], 16B contiguous per lane
    short8 a[4];
    const unsigned short* arow = Ab + (size_t)(rb + ln) * 128 + quad * 8;
#pragma unroll
    for (int ks = 0; ks < 4; ++ks) a[ks] = *(const short8*)(arow + ks * 32);

    f32x4 acc[8];
#pragma unroll
    for (int ct = 0; ct < 8; ++ct) acc[ct] = (f32x4){0.f, 0.f, 0.f, 0.f};

#pragma unroll
    for (int ks = 0; ks < 4; ++ks) {
#pragma unroll
        for (int ct = 0; ct < 8; ++ct) {
            // B[k=quad*8+j][n=ct*16+ln] = Wt[n][k..k+7], 16B contiguous
            short8 b = *(const short8*)(Wt + (ct * 16 + ln) * 136 + ks * 32 + quad * 8);
            acc[ct] = __builtin_amdgcn_mfma_f32_16x16x32_bf16(a[ks], b, acc[ct], 0, 0, 0);
        }
    }

    float dv[4];
#pragma unroll
    for (int r = 0; r < 4; ++r) dv[r] = dinv[rb + quad * 4 + r];
#pragma unroll
    for (int ct = 0; ct < 8; ++ct)
#pragma unroll
        for (int r = 0; r < 4; ++r)
            C[(size_t)(rb + quad * 4 + r) * 128 + ct * 16 + ln] = acc[ct][r] * dv[r];
}

// ---- aggregation: one wave per node, atomic-free scatter->gather ----
// out = relu(dinv[i] * (sum_{e in adj[i]} hs[src] + hs[i]) + bias)
__global__ __launch_bounds__(256) void agg_k(const float* __restrict__ hs,
                                             const int* __restrict__ adj,
                                             const int* __restrict__ cnt,
                                             const float* __restrict__ dinv,
                                             const float* __restrict__ bias,
                                             unsigned short* __restrict__ outb,
                                             float* __restrict__ outf) {
    int wave = threadIdx.x >> 6, lane = threadIdx.x & 63;
    int node = blockIdx.x * 4 + wave;  // grid*4 == N_NODES exactly
    int idx = adj[node * MAXDEG + lane];
    int ec = cnt[node];
    ec = ec < MAXDEG ? ec : MAXDEG;
    const float2* base = (const float2*)hs;  // row = 64 float2
    float2 acc = base[node * 64 + lane];     // self-loop term
    int e = 0;
    for (; e + 4 <= ec; e += 4) {
        int s0 = __shfl(idx, e), s1 = __shfl(idx, e + 1);
        int s2 = __shfl(idx, e + 2), s3 = __shfl(idx, e + 3);
        float2 v0 = base[s0 * 64 + lane], v1 = base[s1 * 64 + lane];
        float2 v2 = base[s2 * 64 + lane], v3 = base[s3 * 64 + lane];
        acc.x += (v0.x + v1.x) + (v2.x + v3.x);
        acc.y += (v0.y + v1.y) + (v2.y + v3.y);
    }
    for (; e < ec; ++e) {
        int s = __shfl(idx, e);
        float2 v = base[s * 64 + lane];
        acc.x += v.x;
        acc.y += v.y;
    }
    float dv = dinv[node];
    float2 bb = ((const float2*)bias)[lane];
    float ox = fmaxf(acc.x * dv + bb.x, 0.f);
    float oy = fmaxf(acc.y * dv + bb.y, 0.f);
    if (outb) {
        ushort2 o;
        o.x = f2bu(ox);
        o.y = f2bu(oy);
        ((ushort2*)outb)[node * 64 + lane] = o;
    } else {
        float2 o;
        o.x = ox;
        o.y = oy;
        ((float2*)outf)[node * 64 + lane] = o;
    }
}

// ---- pooling + readout: one block per graph (batch is sorted) ----
__device__ __forceinline__ int lb(const int* a, int n, int v) {
    int lo = 0, hi = n;
    while (lo < hi) {
        int m = (lo + hi) >> 1;
        if (a[m] < v) lo = m + 1;
        else hi = m;
    }
    return lo;
}

__global__ __launch_bounds__(128) void pool_k(const float* __restrict__ h2,
                                              const int* __restrict__ batch,
                                              const float* __restrict__ Wl,
                                              const float* __restrict__ bl,
                                              float* __restrict__ out) {
    int g = blockIdx.x, t = threadIdx.x;
    int lo = lb(batch, N_NODES, g), hi = lb(batch, N_NODES, g + 1);
    float s = 0.f;
    for (int r = lo; r < hi; ++r) s += h2[(size_t)r * 128 + t];
    float c = (float)(hi - lo);
    float pooled = s / fmaxf(c, 1.f);
    float p = pooled * Wl[t];
#pragma unroll
    for (int o = 32; o > 0; o >>= 1) p += __shfl_down(p, o);
    __shared__ float part[2];
    if ((t & 63) == 0) part[t >> 6] = p;
    __syncthreads();
    if (t == 0) {
        float z = part[0] + part[1] + bl[0];
        out[g] = 1.f / (1.f + expf(-z));
    }
}

extern "C" void kernel_launch(void* const* d_in, const int* in_sizes, int n_in,
                              void* d_out, int out_size, void* d_ws, size_t ws_size,
                              hipStream_t stream) {
    const float* x = (const float*)d_in[0];
    const int* ei = (const int*)d_in[1];
    const int* batch = (const int*)d_in[2];
    const float* W1 = (const float*)d_in[3];
    const float* b1 = (const float*)d_in[4];
    const float* W2 = (const float*)d_in[5];
    const float* b2 = (const float*)d_in[6];
    const float* Wl = (const float*)d_in[7];
    const float* bl = (const float*)d_in[8];
    float* out = (float*)d_out;

    char* ws = (char*)d_ws;
    int* cnt = (int*)(ws + 0);                            // 200000 B
    float* dinv = (float*)(ws + 200192);                  // 200000 B
    int* adj = (int*)(ws + 400384);                       // 12.8 MB
    unsigned short* xb = (unsigned short*)(ws + 13200384);   // 12.8 MB bf16 x
    unsigned short* h1b = (unsigned short*)(ws + 26000384);  // 12.8 MB bf16 h1
    float* hs = (float*)(ws + 38800384);                  // 25.6 MB scaled gemm out
    float* h2f = (float*)(ws + 64400384);                 // 25.6 MB h2

    hipMemsetAsync(cnt, 0, N_NODES * sizeof(int), stream);
    build_adj_k<<<N_EDGES / 256, 256, 0, stream>>>(ei, cnt, adj);
    dinv_k<<<(N_NODES + 255) / 256, 256, 0, stream>>>(cnt, dinv);
    cvt_k<<<(N_NODES * DIM / 4) / 256, 256, 0, stream>>>(x, xb);

    gemm_k<<<(N_NODES + 63) / 64, 256, 0, stream>>>(xb, W1, dinv, hs, N_NODES);
    agg_k<<<N_NODES / 4, 256, 0, stream>>>(hs, adj, cnt, dinv, b1, h1b, nullptr);

    gemm_k<<<(N_NODES + 63) / 64, 256, 0, stream>>>(h1b, W2, dinv, hs, N_NODES);
    agg_k<<<N_NODES / 4, 256, 0, stream>>>(hs, adj, cnt, dinv, b2, nullptr, h2f);

    pool_k<<<NUM_GRAPHS, 128, 0, stream>>>(h2f, batch, Wl, bl, out);
}

// Round 2
// 253.769 us; speedup vs baseline: 1.2356x; 1.2356x over previous
//
#include <hip/hip_runtime.h>
#include <hip/hip_bf16.h>

#define N_NODES 50000
#define N_EDGES 800000
#define NUM_GRAPHS 512
#define MAXDEG 64

typedef short short8 __attribute__((ext_vector_type(8)));
typedef unsigned short u16x8 __attribute__((ext_vector_type(8)));
typedef float f32x4 __attribute__((ext_vector_type(4)));

__device__ __forceinline__ unsigned short f2bu(float f) {
    __hip_bfloat16 h = __float2bfloat16(f);
    return *reinterpret_cast<unsigned short*>(&h);
}
__device__ __forceinline__ float bu2f(unsigned short u) {
    unsigned int v = ((unsigned int)u) << 16;
    float f;
    __builtin_memcpy(&f, &v, 4);
    return f;
}

// ---- adjacency build: count edges per dst, bucket src indices ----
__global__ __launch_bounds__(256) void build_adj_k(const int* __restrict__ ei,
                                                   int* __restrict__ cnt,
                                                   int* __restrict__ adj) {
    int e = blockIdx.x * 256 + threadIdx.x;
    if (e >= N_EDGES) return;
    int s = ei[e];            // row 0: src
    int d = ei[N_EDGES + e];  // row 1: dst
    int slot = atomicAdd(&cnt[d], 1);
    if (slot < MAXDEG) adj[d * MAXDEG + slot] = s;
}

// ---- prep: dinv, self-loop entry, pad adjacency to mult of 4 with zero-row,
//            zero the dummy row of hs ----
__global__ __launch_bounds__(256) void prep_k(const int* __restrict__ cnt,
                                              int* __restrict__ adj,
                                              float* __restrict__ dinv,
                                              unsigned short* __restrict__ hs) {
    if (blockIdx.x == 0 && threadIdx.x < 64)
        ((unsigned int*)(hs + (size_t)N_NODES * 128))[threadIdx.x] = 0u;
    int i = blockIdx.x * 256 + threadIdx.x;
    if (i >= N_NODES) return;
    int c = cnt[i];
    dinv[i] = rsqrtf((float)c + 1.0f);
    int ec = c < MAXDEG - 1 ? c : MAXDEG - 1;
    adj[i * MAXDEG + ec] = i;  // self loop as a regular edge
    int tot = ec + 1;
    int tot4 = (tot + 3) & ~3;
    for (int s = tot; s < tot4; ++s) adj[i * MAXDEG + s] = N_NODES;  // zero row
}

// ---- f32 -> bf16 convert (x features) ----
__global__ __launch_bounds__(256) void cvt_k(const float* __restrict__ x,
                                             unsigned short* __restrict__ xb) {
    int i = blockIdx.x * 256 + threadIdx.x;
    const float4 v = ((const float4*)x)[i];
    ushort4 o;
    o.x = f2bu(v.x); o.y = f2bu(v.y); o.z = f2bu(v.z); o.w = f2bu(v.w);
    ((ushort4*)xb)[i] = o;
}

// ---- W [k][n] f32 -> Wt [n][k] bf16, both weights in one launch ----
__global__ __launch_bounds__(256) void wcvt_k(const float* __restrict__ W1,
                                              const float* __restrict__ W2,
                                              unsigned short* __restrict__ W1t,
                                              unsigned short* __restrict__ W2t) {
    int b = blockIdx.x;
    const float* W = b < 64 ? W1 : W2;
    unsigned short* Wt = b < 64 ? W1t : W2t;
    int idx = (b & 63) * 256 + threadIdx.x;  // 0..16383
    int k = idx >> 7, n = idx & 127;
    Wt[n * 128 + k] = f2bu(W[idx]);
}

// ---- GEMM: C[r][c] = bf16( dinv[r] * sum_k A[r][k]*W[k][c] ), 128 rows/block ----
__global__ __launch_bounds__(256) void gemm_k(const unsigned short* __restrict__ Ab,
                                              const unsigned short* __restrict__ Wt,
                                              const float* __restrict__ dinv,
                                              unsigned short* __restrict__ C) {
    __shared__ unsigned short Wl[128 * 136];
    int t = threadIdx.x;
    for (int idx = t; idx < 2048; idx += 256) {  // 2048 x 16B chunks
        int n = idx >> 4, c = idx & 15;
        *(u16x8*)(Wl + n * 136 + c * 8) = *(const u16x8*)(Wt + n * 128 + c * 8);
    }
    __syncthreads();

    int wave = t >> 6, lane = t & 63, quad = lane >> 4, ln = lane & 15;
    int rb = blockIdx.x * 128 + wave * 16;

    short8 a[2][4];
#pragma unroll
    for (int mt = 0; mt < 2; ++mt) {
        const unsigned short* arow = Ab + (size_t)(rb + mt * 64 + ln) * 128 + quad * 8;
#pragma unroll
        for (int ks = 0; ks < 4; ++ks) a[mt][ks] = *(const short8*)(arow + ks * 32);
    }

    f32x4 acc[2][8];
#pragma unroll
    for (int mt = 0; mt < 2; ++mt)
#pragma unroll
        for (int ct = 0; ct < 8; ++ct) acc[mt][ct] = (f32x4){0.f, 0.f, 0.f, 0.f};

#pragma unroll
    for (int ks = 0; ks < 4; ++ks)
#pragma unroll
        for (int ct = 0; ct < 8; ++ct) {
            short8 b = *(const short8*)(Wl + (ct * 16 + ln) * 136 + ks * 32 + quad * 8);
            acc[0][ct] = __builtin_amdgcn_mfma_f32_16x16x32_bf16(a[0][ks], b, acc[0][ct], 0, 0, 0);
            acc[1][ct] = __builtin_amdgcn_mfma_f32_16x16x32_bf16(a[1][ks], b, acc[1][ct], 0, 0, 0);
        }

#pragma unroll
    for (int mt = 0; mt < 2; ++mt) {
#pragma unroll
        for (int rr = 0; rr < 4; ++rr) {
            int r = rb + mt * 64 + quad * 4 + rr;
            if (r >= N_NODES) continue;
            float dv = dinv[r];
#pragma unroll
            for (int ct = 0; ct < 8; ++ct)
                C[(size_t)r * 128 + ct * 16 + ln] = f2bu(acc[mt][ct][rr] * dv);
        }
    }
}

// ---- aggregation: one wave/node; each quad gathers one 256B bf16 row (16B/lane) ----
// out = bf16( relu(dinv[i] * sum_{adj} hs[src] + bias) )   (self already in adj)
__global__ __launch_bounds__(256) void agg_k(const unsigned short* __restrict__ hs,
                                             const int* __restrict__ adj,
                                             const int* __restrict__ cnt,
                                             const float* __restrict__ dinv,
                                             const float* __restrict__ bias,
                                             unsigned short* __restrict__ out) {
    int wave = threadIdx.x >> 6, lane = threadIdx.x & 63;
    int node = blockIdx.x * 4 + wave;  // grid*4 == N_NODES exactly
    int quad = lane >> 4, fl = lane & 15;
    int idx = adj[node * MAXDEG + lane];
    int c = cnt[node];
    int ec = c < MAXDEG - 1 ? c : MAXDEG - 1;
    int iters = (ec + 1 + 3) >> 2;  // (edges + self) rounded up to 4

    float acc[8];
#pragma unroll
    for (int j = 0; j < 8; ++j) acc[j] = 0.f;

    for (int i = 0; i < iters; ++i) {
        int s = __shfl(idx, i * 4 + quad, 64);
        u16x8 v = *(const u16x8*)(hs + (size_t)s * 128 + fl * 8);
#pragma unroll
        for (int j = 0; j < 8; ++j) acc[j] += bu2f(v[j]);
    }

#pragma unroll
    for (int j = 0; j < 8; ++j) {
        acc[j] += __shfl_xor(acc[j], 16, 64);
        acc[j] += __shfl_xor(acc[j], 32, 64);
    }

    if (quad == 0) {
        float dv = dinv[node];
        float4 b0 = *(const float4*)(bias + fl * 8);
        float4 b1 = *(const float4*)(bias + fl * 8 + 4);
        u16x8 o;
        o[0] = f2bu(fmaxf(acc[0] * dv + b0.x, 0.f));
        o[1] = f2bu(fmaxf(acc[1] * dv + b0.y, 0.f));
        o[2] = f2bu(fmaxf(acc[2] * dv + b0.z, 0.f));
        o[3] = f2bu(fmaxf(acc[3] * dv + b0.w, 0.f));
        o[4] = f2bu(fmaxf(acc[4] * dv + b1.x, 0.f));
        o[5] = f2bu(fmaxf(acc[5] * dv + b1.y, 0.f));
        o[6] = f2bu(fmaxf(acc[6] * dv + b1.z, 0.f));
        o[7] = f2bu(fmaxf(acc[7] * dv + b1.w, 0.f));
        *(u16x8*)(out + (size_t)node * 128 + fl * 8) = o;
    }
}

// ---- pooling + readout: one block (256 thr = 128 feat x 2 stripes) per graph ----
__device__ __forceinline__ int lb(const int* a, int n, int v) {
    int lo = 0, hi = n;
    while (lo < hi) {
        int m = (lo + hi) >> 1;
        if (a[m] < v) lo = m + 1;
        else hi = m;
    }
    return lo;
}

__global__ __launch_bounds__(256) void pool_k(const unsigned short* __restrict__ h2,
                                              const int* __restrict__ batch,
                                              const float* __restrict__ Wl,
                                              const float* __restrict__ bl,
                                              float* __restrict__ out) {
    __shared__ float buf[256];
    __shared__ float part[2];
    int g = blockIdx.x, t = threadIdx.x;
    int f = t & 127, stripe = t >> 7;
    int lo = lb(batch, N_NODES, g), hi = lb(batch, N_NODES, g + 1);
    float s = 0.f;
    for (int r = lo + stripe; r < hi; r += 2)
        s += bu2f(h2[(size_t)r * 128 + f]);
    buf[t] = s;
    __syncthreads();
    if (t < 128) {
        float cf = (float)(hi - lo);
        float pooled = (buf[t] + buf[t + 128]) / fmaxf(cf, 1.f);
        float p = pooled * Wl[t];
#pragma unroll
        for (int o = 32; o > 0; o >>= 1) p += __shfl_down(p, o, 64);
        if ((t & 63) == 0) part[t >> 6] = p;
    }
    __syncthreads();
    if (t == 0) out[g] = 1.f / (1.f + expf(-(part[0] + part[1] + bl[0])));
}

extern "C" void kernel_launch(void* const* d_in, const int* in_sizes, int n_in,
                              void* d_out, int out_size, void* d_ws, size_t ws_size,
                              hipStream_t stream) {
    const float* x = (const float*)d_in[0];
    const int* ei = (const int*)d_in[1];
    const int* batch = (const int*)d_in[2];
    const float* W1 = (const float*)d_in[3];
    const float* b1 = (const float*)d_in[4];
    const float* W2 = (const float*)d_in[5];
    const float* b2 = (const float*)d_in[6];
    const float* Wl = (const float*)d_in[7];
    const float* bl = (const float*)d_in[8];
    float* out = (float*)d_out;

    char* ws = (char*)d_ws;
    int* cnt = (int*)(ws + 0);                              // 200000 B
    float* dinv = (float*)(ws + 200192);                    // 200000 B
    int* adj = (int*)(ws + 400384);                         // 12.8 MB
    unsigned short* xb = (unsigned short*)(ws + 13200384);  // 12.8 MB bf16 x
    unsigned short* W1t = (unsigned short*)(ws + 26000384); // 32 KB
    unsigned short* W2t = (unsigned short*)(ws + 26033152); // 32 KB
    unsigned short* hs = (unsigned short*)(ws + 26065920);  // (N+1)x128 bf16 = 12.80 MB
    unsigned short* h1b = (unsigned short*)(ws + 38866432); // 12.8 MB
    unsigned short* h2b = (unsigned short*)(ws + 51666432); // 12.8 MB

    hipMemsetAsync(cnt, 0, N_NODES * sizeof(int), stream);
    build_adj_k<<<N_EDGES / 256, 256, 0, stream>>>(ei, cnt, adj);
    prep_k<<<(N_NODES + 255) / 256, 256, 0, stream>>>(cnt, adj, dinv, hs);
    cvt_k<<<(N_NODES * 128 / 4) / 256, 256, 0, stream>>>(x, xb);
    wcvt_k<<<128, 256, 0, stream>>>(W1, W2, W1t, W2t);

    gemm_k<<<(N_NODES + 127) / 128, 256, 0, stream>>>(xb, W1t, dinv, hs);
    agg_k<<<N_NODES / 4, 256, 0, stream>>>(hs, adj, cnt, dinv, b1, h1b);

    gemm_k<<<(N_NODES + 127) / 128, 256, 0, stream>>>(h1b, W2t, dinv, hs);
    agg_k<<<N_NODES / 4, 256, 0, stream>>>(hs, adj, cnt, dinv, b2, h2b);

    pool_k<<<NUM_GRAPHS, 256, 0, stream>>>(h2b, batch, Wl, bl, out);
}

// Round 3
// 239.322 us; speedup vs baseline: 1.3102x; 1.0604x over previous
//
#include <hip/hip_runtime.h>
#include <hip/hip_bf16.h>

#define N_NODES 50000
#define N_EDGES 800000
#define NUM_GRAPHS 512
#define MAXDEG 64

typedef short short8 __attribute__((ext_vector_type(8)));
typedef unsigned short u16x8 __attribute__((ext_vector_type(8)));
typedef float f32x4 __attribute__((ext_vector_type(4)));

__device__ __forceinline__ unsigned short f2bu(float f) {
    __hip_bfloat16 h = __float2bfloat16(f);
    return *reinterpret_cast<unsigned short*>(&h);
}
__device__ __forceinline__ float bu2f(unsigned short u) {
    unsigned int v = ((unsigned int)u) << 16;
    float f;
    __builtin_memcpy(&f, &v, 4);
    return f;
}

// ---- adjacency build: 4 edges/thread for MLP on the atomic+scatter chain ----
__global__ __launch_bounds__(256) void build_adj_k(const int* __restrict__ ei,
                                                   int* __restrict__ cnt,
                                                   unsigned short* __restrict__ adj) {
    int e0 = (blockIdx.x * 256 + threadIdx.x) * 4;
    if (e0 >= N_EDGES) return;
    int4 s4 = *(const int4*)(ei + e0);
    int4 d4 = *(const int4*)(ei + N_EDGES + e0);
    int sl0 = atomicAdd(&cnt[d4.x], 1);
    int sl1 = atomicAdd(&cnt[d4.y], 1);
    int sl2 = atomicAdd(&cnt[d4.z], 1);
    int sl3 = atomicAdd(&cnt[d4.w], 1);
    if (sl0 < MAXDEG) adj[d4.x * MAXDEG + sl0] = (unsigned short)s4.x;
    if (sl1 < MAXDEG) adj[d4.y * MAXDEG + sl1] = (unsigned short)s4.y;
    if (sl2 < MAXDEG) adj[d4.z * MAXDEG + sl2] = (unsigned short)s4.z;
    if (sl3 < MAXDEG) adj[d4.w * MAXDEG + sl3] = (unsigned short)s4.w;
}

// ---- prep: dinv, self-loop entry, pad to mult of 4 with zero-row sentinel ----
__global__ __launch_bounds__(256) void prep_k(const int* __restrict__ cnt,
                                              unsigned short* __restrict__ adj,
                                              float* __restrict__ dinv,
                                              unsigned short* __restrict__ hs) {
    if (blockIdx.x == 0 && threadIdx.x < 64)
        ((unsigned int*)(hs + (size_t)N_NODES * 128))[threadIdx.x] = 0u;
    int i = blockIdx.x * 256 + threadIdx.x;
    if (i >= N_NODES) return;
    int c = cnt[i];
    dinv[i] = rsqrtf((float)c + 1.0f);
    int ec = c < MAXDEG - 1 ? c : MAXDEG - 1;
    adj[i * MAXDEG + ec] = (unsigned short)i;  // self loop as a regular edge
    int tot = ec + 1;
    int tot4 = (tot + 3) & ~3;
    for (int s = tot; s < tot4; ++s) adj[i * MAXDEG + s] = (unsigned short)N_NODES;
}

// ---- W [k][n] f32 -> Wt [n][k] bf16, both weights in one launch ----
__global__ __launch_bounds__(256) void wcvt_k(const float* __restrict__ W1,
                                              const float* __restrict__ W2,
                                              unsigned short* __restrict__ W1t,
                                              unsigned short* __restrict__ W2t) {
    int b = blockIdx.x;
    const float* W = b < 64 ? W1 : W2;
    unsigned short* Wt = b < 64 ? W1t : W2t;
    int idx = (b & 63) * 256 + threadIdx.x;  // 0..16383
    int k = idx >> 7, n = idx & 127;
    Wt[n * 128 + k] = f2bu(W[idx]);
}

// ---- GEMM: C[r][c] = bf16( dinv[r] * sum_k A[r][k]*W[k][c] ), 128 rows/block ----
// F32A: A is fp32 (converted to bf16 fragments in-register).
template <bool F32A>
__global__ __launch_bounds__(256) void gemm_k(const void* __restrict__ Ap,
                                              const unsigned short* __restrict__ Wt,
                                              const float* __restrict__ dinv,
                                              unsigned short* __restrict__ C) {
    __shared__ unsigned short Wl[128 * 136];
    int t = threadIdx.x;
    for (int idx = t; idx < 2048; idx += 256) {  // 2048 x 16B chunks
        int n = idx >> 4, c = idx & 15;
        *(u16x8*)(Wl + n * 136 + c * 8) = *(const u16x8*)(Wt + n * 128 + c * 8);
    }
    __syncthreads();

    int wave = t >> 6, lane = t & 63, quad = lane >> 4, ln = lane & 15;
    int rb = blockIdx.x * 128 + wave * 16;

    short8 a[2][4];
#pragma unroll
    for (int mt = 0; mt < 2; ++mt) {
        int r = rb + mt * 64 + ln;
        r = r < N_NODES ? r : N_NODES - 1;  // clamp: avoid OOB reads of input
        if (F32A) {
            const float* arow = (const float*)Ap + (size_t)r * 128 + quad * 8;
#pragma unroll
            for (int ks = 0; ks < 4; ++ks) {
                float4 v0 = *(const float4*)(arow + ks * 32);
                float4 v1 = *(const float4*)(arow + ks * 32 + 4);
                short8 av;
                av[0] = (short)f2bu(v0.x); av[1] = (short)f2bu(v0.y);
                av[2] = (short)f2bu(v0.z); av[3] = (short)f2bu(v0.w);
                av[4] = (short)f2bu(v1.x); av[5] = (short)f2bu(v1.y);
                av[6] = (short)f2bu(v1.z); av[7] = (short)f2bu(v1.w);
                a[mt][ks] = av;
            }
        } else {
            const unsigned short* arow = (const unsigned short*)Ap + (size_t)r * 128 + quad * 8;
#pragma unroll
            for (int ks = 0; ks < 4; ++ks) a[mt][ks] = *(const short8*)(arow + ks * 32);
        }
    }

    f32x4 acc[2][8];
#pragma unroll
    for (int mt = 0; mt < 2; ++mt)
#pragma unroll
        for (int ct = 0; ct < 8; ++ct) acc[mt][ct] = (f32x4){0.f, 0.f, 0.f, 0.f};

#pragma unroll
    for (int ks = 0; ks < 4; ++ks)
#pragma unroll
        for (int ct = 0; ct < 8; ++ct) {
            short8 b = *(const short8*)(Wl + (ct * 16 + ln) * 136 + ks * 32 + quad * 8);
            acc[0][ct] = __builtin_amdgcn_mfma_f32_16x16x32_bf16(a[0][ks], b, acc[0][ct], 0, 0, 0);
            acc[1][ct] = __builtin_amdgcn_mfma_f32_16x16x32_bf16(a[1][ks], b, acc[1][ct], 0, 0, 0);
        }

#pragma unroll
    for (int mt = 0; mt < 2; ++mt) {
#pragma unroll
        for (int rr = 0; rr < 4; ++rr) {
            int r = rb + mt * 64 + quad * 4 + rr;
            if (r >= N_NODES) continue;
            float dv = dinv[r];
#pragma unroll
            for (int ct = 0; ct < 8; ++ct)
                C[(size_t)r * 128 + ct * 16 + ln] = f2bu(acc[mt][ct][rr] * dv);
        }
    }
}

// ---- aggregation: one wave/node; each quad gathers one 256B bf16 row (16B/lane) ----
__global__ __launch_bounds__(256) void agg_k(const unsigned short* __restrict__ hs,
                                             const unsigned short* __restrict__ adj,
                                             const int* __restrict__ cnt,
                                             const float* __restrict__ dinv,
                                             const float* __restrict__ bias,
                                             unsigned short* __restrict__ out) {
    int wave = threadIdx.x >> 6, lane = threadIdx.x & 63;
    int node = blockIdx.x * 4 + wave;  // grid*4 == N_NODES exactly
    int quad = lane >> 4, fl = lane & 15;
    int idx = (int)adj[node * MAXDEG + lane];
    int c = cnt[node];
    int ec = c < MAXDEG - 1 ? c : MAXDEG - 1;
    int iters = (ec + 1 + 3) >> 2;  // (edges + self) rounded up to 4

    float acc[8];
#pragma unroll
    for (int j = 0; j < 8; ++j) acc[j] = 0.f;

    for (int i = 0; i < iters; ++i) {
        int s = __shfl(idx, i * 4 + quad, 64);
        u16x8 v = *(const u16x8*)(hs + (size_t)s * 128 + fl * 8);
#pragma unroll
        for (int j = 0; j < 8; ++j) acc[j] += bu2f(v[j]);
    }

#pragma unroll
    for (int j = 0; j < 8; ++j) {
        acc[j] += __shfl_xor(acc[j], 16, 64);
        acc[j] += __shfl_xor(acc[j], 32, 64);
    }

    if (quad == 0) {
        float dv = dinv[node];
        float4 b0 = *(const float4*)(bias + fl * 8);
        float4 b1 = *(const float4*)(bias + fl * 8 + 4);
        u16x8 o;
        o[0] = f2bu(fmaxf(acc[0] * dv + b0.x, 0.f));
        o[1] = f2bu(fmaxf(acc[1] * dv + b0.y, 0.f));
        o[2] = f2bu(fmaxf(acc[2] * dv + b0.z, 0.f));
        o[3] = f2bu(fmaxf(acc[3] * dv + b0.w, 0.f));
        o[4] = f2bu(fmaxf(acc[4] * dv + b1.x, 0.f));
        o[5] = f2bu(fmaxf(acc[5] * dv + b1.y, 0.f));
        o[6] = f2bu(fmaxf(acc[6] * dv + b1.z, 0.f));
        o[7] = f2bu(fmaxf(acc[7] * dv + b1.w, 0.f));
        *(u16x8*)(out + (size_t)node * 128 + fl * 8) = o;
    }
}

// ---- pooling + readout: one block (256 thr = 128 feat x 2 stripes) per graph ----
__device__ __forceinline__ int lb(const int* a, int n, int v) {
    int lo = 0, hi = n;
    while (lo < hi) {
        int m = (lo + hi) >> 1;
        if (a[m] < v) lo = m + 1;
        else hi = m;
    }
    return lo;
}

__global__ __launch_bounds__(256) void pool_k(const unsigned short* __restrict__ h2,
                                              const int* __restrict__ batch,
                                              const float* __restrict__ Wl,
                                              const float* __restrict__ bl,
                                              float* __restrict__ out) {
    __shared__ float buf[256];
    __shared__ float part[2];
    int g = blockIdx.x, t = threadIdx.x;
    int f = t & 127, stripe = t >> 7;
    int lo = lb(batch, N_NODES, g), hi = lb(batch, N_NODES, g + 1);
    float s = 0.f;
    for (int r = lo + stripe; r < hi; r += 2)
        s += bu2f(h2[(size_t)r * 128 + f]);
    buf[t] = s;
    __syncthreads();
    if (t < 128) {
        float cf = (float)(hi - lo);
        float pooled = (buf[t] + buf[t + 128]) / fmaxf(cf, 1.f);
        float p = pooled * Wl[t];
#pragma unroll
        for (int o = 32; o > 0; o >>= 1) p += __shfl_down(p, o, 64);
        if ((t & 63) == 0) part[t >> 6] = p;
    }
    __syncthreads();
    if (t == 0) out[g] = 1.f / (1.f + expf(-(part[0] + part[1] + bl[0])));
}

extern "C" void kernel_launch(void* const* d_in, const int* in_sizes, int n_in,
                              void* d_out, int out_size, void* d_ws, size_t ws_size,
                              hipStream_t stream) {
    const float* x = (const float*)d_in[0];
    const int* ei = (const int*)d_in[1];
    const int* batch = (const int*)d_in[2];
    const float* W1 = (const float*)d_in[3];
    const float* b1 = (const float*)d_in[4];
    const float* W2 = (const float*)d_in[5];
    const float* b2 = (const float*)d_in[6];
    const float* Wl = (const float*)d_in[7];
    const float* bl = (const float*)d_in[8];
    float* out = (float*)d_out;

    char* ws = (char*)d_ws;
    int* cnt = (int*)(ws + 0);                               // 200000 B
    float* dinv = (float*)(ws + 200192);                     // 200000 B
    unsigned short* adj = (unsigned short*)(ws + 400384);    // 6.4 MB
    unsigned short* W1t = (unsigned short*)(ws + 6800384);   // 32 KB
    unsigned short* W2t = (unsigned short*)(ws + 6833152);   // 32 KB
    unsigned short* hs = (unsigned short*)(ws + 6865920);    // (N+1)x128 bf16
    unsigned short* h1b = (unsigned short*)(ws + 19666432);  // 12.8 MB
    unsigned short* h2b = (unsigned short*)(ws + 32466432);  // 12.8 MB

    hipMemsetAsync(cnt, 0, N_NODES * sizeof(int), stream);
    build_adj_k<<<(N_EDGES / 4 + 255) / 256, 256, 0, stream>>>(ei, cnt, adj);
    prep_k<<<(N_NODES + 255) / 256, 256, 0, stream>>>(cnt, adj, dinv, hs);
    wcvt_k<<<128, 256, 0, stream>>>(W1, W2, W1t, W2t);

    gemm_k<true><<<(N_NODES + 127) / 128, 256, 0, stream>>>(x, W1t, dinv, hs);
    agg_k<<<N_NODES / 4, 256, 0, stream>>>(hs, adj, cnt, dinv, b1, h1b);

    gemm_k<false><<<(N_NODES + 127) / 128, 256, 0, stream>>>(h1b, W2t, dinv, hs);
    agg_k<<<N_NODES / 4, 256, 0, stream>>>(hs, adj, cnt, dinv, b2, h2b);

    pool_k<<<NUM_GRAPHS, 256, 0, stream>>>(h2b, batch, Wl, bl, out);
}